// Round 1
// baseline (1069.373 us; speedup 1.0000x reference)
//
#include <hip/hip_runtime.h>

#define Bc 8
#define Cc 64
#define Nn 4096
#define Oc 64
#define Kk 20

#define NEGINF (-__builtin_inff())

// ---- workspace layout (float offsets) ----
#define WS_XX    0          // 32768  : per-point squared norms
#define WS_M1    32768      // 4096   : w1a - w1b  (64x64)
#define WS_M2    36864      // 4096   : w1b        (64x64)
#define WS_U     40960      // 2097152: U[b,n,c'] = M1 . x_n
#define WS_Y     2138112    // 2097152: Y[b,n,c'] = M2 . x_n
#define WS_PS    4235264    // 16384  : per-block partial sums   (256 x 64)
#define WS_PQ    4251648    // 16384  : per-block partial sumsq  (256 x 64)
#define WS_SC    4268032    // 64     : BN scale
#define WS_SH    4268096    // 64     : BN shift
#define WS_IDX   4268160    // 655360 ints : top-K neighbor indices
// total: ~19.7 MB

struct __align__(16) F4 { float v[4]; };

// swizzled physical index within a 4096-float distance row: keeps both the
// lane-strided initial scan and the chunk rescan <=2-way bank-conflict free
__device__ __forceinline__ int physJ(int j) {
    return (j & ~63) | ((j ^ (j >> 6)) & 63);
}

// ---------------- prep: M1/M2 from w1 ----------------
__global__ void k_prep(const float* __restrict__ w1, float* __restrict__ ws) {
    int g = blockIdx.x * 256 + threadIdx.x;   // 4096
    int cp = g >> 6, c = g & 63;
    float a = w1[cp * 128 + c];
    float b = w1[cp * 128 + 64 + c];
    ws[WS_M1 + g] = a - b;
    ws[WS_M2 + g] = b;
}

// ---------------- squared norms ----------------
__global__ void k_xx(const float* __restrict__ x, float* __restrict__ ws) {
    int g = blockIdx.x * 256 + threadIdx.x;   // 32768
    int b = g >> 12, n = g & 4095;
    const float* xb = x + (size_t)b * Cc * Nn + n;
    float s = 0.f;
    #pragma unroll
    for (int c = 0; c < 64; ++c) { float v = xb[(size_t)c * Nn]; s = fmaf(v, v, s); }
    ws[WS_XX + g] = s;
}

// ---------------- fused pairwise-distance + top-K ----------------
// grid 8192: block handles batch b, rows i0..i0+3 (4 rows x 4096 dists in LDS)
__global__ __launch_bounds__(256, 2) void k_dist_topk(const float* __restrict__ x,
                                                      const float* __restrict__ ws,
                                                      int* __restrict__ idxo) {
    __shared__ float dist[4 * 4096];          // exactly 64 KiB
    const int t   = threadIdx.x;
    const int blk = blockIdx.x;
    const int b   = blk >> 10;
    const int i0  = (blk & 1023) << 2;
    const float* xb  = x + (size_t)b * Cc * Nn;
    const float* xxp = ws + WS_XX + b * Nn;

    float xxi[4];
    #pragma unroll
    for (int r = 0; r < 4; ++r) xxi[r] = xxp[i0 + r];   // uniform -> s_load

    for (int jj = 0; jj < 4; ++jj) {
        float acc[4][4];
        #pragma unroll
        for (int r = 0; r < 4; ++r)
            #pragma unroll
            for (int q = 0; q < 4; ++q) acc[r][q] = 0.f;
        const int jb = jj * 1024 + t * 4;
        #pragma unroll 4
        for (int c = 0; c < 64; ++c) {
            const float* row = xb + (size_t)c * Nn;
            F4 xj = *(const F4*)(row + jb);   // coalesced dwordx4
            F4 xi = *(const F4*)(row + i0);   // block-uniform -> scalar load
            #pragma unroll
            for (int r = 0; r < 4; ++r)
                #pragma unroll
                for (int q = 0; q < 4; ++q)
                    acc[r][q] = fmaf(xi.v[r], xj.v[q], acc[r][q]);
        }
        F4 xxj = *(const F4*)(xxp + jb);
        #pragma unroll
        for (int q = 0; q < 4; ++q)
            #pragma unroll
            for (int r = 0; r < 4; ++r) {
                // pdist = 2*dot - xx_i - xx_j  (diag exactly 0)
                float pd = fmaf(2.f, acc[r][q], -xxi[r]) - xxj.v[q];
                dist[r * 4096 + physJ(jb + q)] = pd;
            }
    }
    __syncthreads();

    // top-K: wave w owns row w; lane owns contiguous chunk [lane*64, lane*64+64)
    const int w = t >> 6, lane = t & 63;
    float* drow = dist + w * 4096;

    float mx = NEGINF; int mj = 0;
    for (int m = 0; m < 64; ++m) {
        int j = (lane << 6) + m;
        float v = drow[(lane << 6) + (m ^ lane)];
        if (v > mx) { mx = v; mj = j; }       // ascending j -> lowest-index tie
    }
    const int outbase = ((b << 12) + i0 + w) * Kk;

    for (int k = 0; k < Kk; ++k) {
        // global argmax across 64 chunk maxima
        float bv = mx; int bj = mj;
        #pragma unroll
        for (int s = 1; s < 64; s <<= 1) {
            float ov = __shfl_xor(bv, s);
            int   oj = __shfl_xor(bj, s);
            if (ov > bv || (ov == bv && oj < bj)) { bv = ov; bj = oj; }
        }
        if (lane == 0) {
            idxo[outbase + k] = bj;
            drow[physJ(bj)] = NEGINF;         // remove winner
        }
        __syncthreads();
        // rescan winning chunk cooperatively (lane m reads element m)
        int cw = bj >> 6;
        int j2 = (cw << 6) + lane;
        float nv = drow[(cw << 6) + (lane ^ cw)];
        int nj = j2;
        #pragma unroll
        for (int s = 1; s < 64; s <<= 1) {
            float ov = __shfl_xor(nv, s);
            int   oj = __shfl_xor(nj, s);
            if (ov > nv || (ov == nv && oj < nj)) { nv = ov; nj = oj; }
        }
        if (lane == cw) { mx = nv; mj = nj; }
    }
}

// ---------------- U = M1.x, Y = M2.x (tiny GEMMs) ----------------
__global__ __launch_bounds__(256) void k_uy(const float* __restrict__ x,
                                            float* __restrict__ ws) {
    __shared__ float xts[64 * 68];
    __shared__ float m1s[64 * 65];
    __shared__ float m2s[64 * 65];
    const int t = threadIdx.x;
    const int b  = blockIdx.x >> 6;
    const int i0 = (blockIdx.x & 63) << 6;
    const float* xb = x + (size_t)b * Cc * Nn;
    const int lane = t & 63, q = t >> 6;

    #pragma unroll
    for (int cc = 0; cc < 16; ++cc) {
        int c = q + cc * 4;
        xts[c * 68 + lane] = xb[(size_t)c * Nn + i0 + lane];
        int gidx = cc * 256 + t;
        int cp = gidx >> 6, c2 = gidx & 63;
        m1s[cp * 65 + c2] = ws[WS_M1 + gidx];
        m2s[cp * 65 + c2] = ws[WS_M2 + gidx];
    }
    __syncthreads();

    float accU[16], accY[16];
    #pragma unroll
    for (int m = 0; m < 16; ++m) { accU[m] = 0.f; accY[m] = 0.f; }

    #pragma unroll 4
    for (int c = 0; c < 64; ++c) {
        float a1 = m1s[lane * 65 + c];        // distinct banks (pad 65)
        float a2 = m2s[lane * 65 + c];
        const F4* xr = (const F4*)&xts[c * 68 + q * 16];  // wave-uniform broadcast
        #pragma unroll
        for (int mm = 0; mm < 4; ++mm) {
            F4 xv = xr[mm];
            #pragma unroll
            for (int ii = 0; ii < 4; ++ii) {
                accU[mm * 4 + ii] = fmaf(a1, xv.v[ii], accU[mm * 4 + ii]);
                accY[mm * 4 + ii] = fmaf(a2, xv.v[ii], accY[mm * 4 + ii]);
            }
        }
    }
    float* Up = ws + WS_U + ((size_t)(b << 12) + i0 + q * 16) * 64 + lane;
    float* Yp = ws + WS_Y + ((size_t)(b << 12) + i0 + q * 16) * 64 + lane;
    #pragma unroll
    for (int m = 0; m < 16; ++m) { Up[(size_t)m * 64] = accU[m]; Yp[(size_t)m * 64] = accY[m]; }
}

// ---------------- BN statistics (deterministic two-stage) ----------------
__global__ __launch_bounds__(256) void k_stats(const float* __restrict__ wsf,
                                               const int* __restrict__ idxI,
                                               float* __restrict__ psum,
                                               float* __restrict__ psq) {
    const int t = threadIdx.x;
    const int c = t & 63, w = t >> 6;
    const int b = blockIdx.x >> 5;
    const int n0 = (blockIdx.x & 31) << 7;    // 128 n per block
    const float* U = wsf + WS_U;
    const float* Y = wsf + WS_Y;
    float s = 0.f, s2 = 0.f;
    for (int m = 0; m < 640; ++m) {
        int p = w + (m << 2);                 // p < 2560
        int nl = p / 20, k = p - nl * 20;
        int n = (b << 12) + n0 + nl;
        int j = idxI[n * 20 + k];             // wave-uniform
        float h = U[(size_t)n * 64 + c] + Y[(size_t)((b << 12) + j) * 64 + c];
        s += h; s2 = fmaf(h, h, s2);
    }
    __shared__ float rs[4][64], rq[4][64];
    rs[w][c] = s; rq[w][c] = s2;
    __syncthreads();
    if (t < 64) {
        float a  = rs[0][t] + rs[1][t] + rs[2][t] + rs[3][t];
        float b2 = rq[0][t] + rq[1][t] + rq[2][t] + rq[3][t];
        psum[blockIdx.x * 64 + t] = a;
        psq [blockIdx.x * 64 + t] = b2;
    }
}

__global__ void k_fin(const float* __restrict__ psum, const float* __restrict__ psq,
                      const float* __restrict__ gamma, const float* __restrict__ beta,
                      float* __restrict__ sc, float* __restrict__ sh) {
    int c = threadIdx.x;                      // 64 threads
    float s = 0.f, q = 0.f;
    for (int i = 0; i < 256; ++i) { s += psum[i * 64 + c]; q += psq[i * 64 + c]; }
    const float inv = 1.f / 655360.f;
    float mean = s * inv;
    float var  = q * inv - mean * mean;
    float scale = gamma[c] * rsqrtf(var + 1e-5f);
    sc[c] = scale;
    sh[c] = beta[c] - mean * scale;
}

// ---------------- BN+relu+GEMM(w2)+max_k+transpose ----------------
__global__ __launch_bounds__(256) void k_out(const float* __restrict__ wsf,
                                             const int* __restrict__ idxI,
                                             const float* __restrict__ w2,
                                             float* __restrict__ out) {
    __shared__ float gbuf[4 * 20 * 64];       // 20 KiB (per-wave private regions)
    __shared__ float outT[64 * 65];           // 16.6 KiB transposed staging
    const int t = threadIdx.x;
    const int lane = t & 63, w = t >> 6;
    const int b = blockIdx.x >> 6;
    const int n0 = (blockIdx.x & 63) << 6;
    const float* U = wsf + WS_U;
    const float* Y = wsf + WS_Y;

    float w2r[64];                            // own output row of w2 in VGPRs
    #pragma unroll
    for (int cc = 0; cc < 16; ++cc) {
        F4 v = *(const F4*)&w2[lane * 64 + cc * 4];
        #pragma unroll
        for (int ii = 0; ii < 4; ++ii) w2r[cc * 4 + ii] = v.v[ii];
    }
    const float sc = wsf[WS_SC + lane];
    const float sh = wsf[WS_SH + lane];

    for (int sg = 0; sg < 16; ++sg) {
        const int n = (b << 12) + n0 + sg * 4 + w;   // wave w owns one n
        const float uv = U[(size_t)n * 64 + lane];
        const int* ip = idxI + n * 20;
        for (int k = 0; k < 20; ++k) {
            int j = ip[k];                            // wave-uniform
            float hv = uv + Y[(size_t)((b << 12) + j) * 64 + lane];
            float g = fmaf(hv, sc, sh);
            gbuf[(w * 20 + k) * 64 + lane] = fmaxf(g, 0.f);
        }
        __syncthreads();
        float vmax = NEGINF;
        for (int k = 0; k < 20; ++k) {
            const F4* gp = (const F4*)&gbuf[(w * 20 + k) * 64];
            float a = 0.f;
            #pragma unroll
            for (int cc = 0; cc < 16; ++cc) {
                F4 gv = gp[cc];                       // broadcast b128
                a = fmaf(gv.v[0], w2r[cc * 4 + 0], a);
                a = fmaf(gv.v[1], w2r[cc * 4 + 1], a);
                a = fmaf(gv.v[2], w2r[cc * 4 + 2], a);
                a = fmaf(gv.v[3], w2r[cc * 4 + 3], a);
            }
            vmax = fmaxf(vmax, a);
        }
        outT[lane * 65 + sg * 4 + w] = vmax;          // o = lane
        __syncthreads();
    }
    #pragma unroll
    for (int m = 0; m < 16; ++m) {
        int row = w + m * 4;                          // row = o
        out[((size_t)(b * 64 + row)) * 4096 + n0 + lane] = outT[row * 65 + lane];
    }
}

// ---------------- launch ----------------
extern "C" void kernel_launch(void* const* d_in, const int* in_sizes, int n_in,
                              void* d_out, int out_size, void* d_ws, size_t ws_size,
                              hipStream_t stream) {
    (void)in_sizes; (void)n_in; (void)out_size; (void)ws_size;
    const float* x     = (const float*)d_in[0];
    const float* w1    = (const float*)d_in[1];
    const float* gamma = (const float*)d_in[2];
    const float* beta  = (const float*)d_in[3];
    const float* w2    = (const float*)d_in[4];
    float* out = (float*)d_out;
    float* wsf = (float*)d_ws;
    int*  idxI = (int*)(wsf + WS_IDX);

    hipLaunchKernelGGL(k_prep,      dim3(16),   dim3(256), 0, stream, w1, wsf);
    hipLaunchKernelGGL(k_xx,        dim3(128),  dim3(256), 0, stream, x, wsf);
    hipLaunchKernelGGL(k_dist_topk, dim3(8192), dim3(256), 0, stream, x, wsf, idxI);
    hipLaunchKernelGGL(k_uy,        dim3(512),  dim3(256), 0, stream, x, wsf);
    hipLaunchKernelGGL(k_stats,     dim3(256),  dim3(256), 0, stream, wsf, idxI,
                       wsf + WS_PS, wsf + WS_PQ);
    hipLaunchKernelGGL(k_fin,       dim3(1),    dim3(64),  0, stream,
                       wsf + WS_PS, wsf + WS_PQ, gamma, beta, wsf + WS_SC, wsf + WS_SH);
    hipLaunchKernelGGL(k_out,       dim3(512),  dim3(256), 0, stream, wsf, idxI, w2, out);
}

// Round 2
// 883.233 us; speedup vs baseline: 1.2107x; 1.2107x over previous
//
#include <hip/hip_runtime.h>

#define Bc 8
#define Cc 64
#define Nn 4096
#define Oc 64
#define Kk 20

#define NEGINF (-__builtin_inff())

// ---- workspace layout (float offsets) ----
#define WS_XX    0          // 32768  : per-point squared norms
#define WS_M1    32768      // 4096   : w1a - w1b  (64x64)
#define WS_M2    36864      // 4096   : w1b        (64x64)
#define WS_U     40960      // 2097152: U[b,n,c'] = M1 . x_n
#define WS_Y     2138112    // 2097152: Y[b,n,c'] = M2 . x_n
#define WS_PS    4235264    // 65536  : per-block partial sums   (1024 x 64)
#define WS_PQ    4300800    // 65536  : per-block partial sumsq  (1024 x 64)
#define WS_SC    4366336    // 64     : BN scale
#define WS_SH    4366400    // 64     : BN shift
#define WS_IDX   4366464    // 655360 ints : top-K neighbor indices
// total ~20.1 MB

struct __align__(16) F4 { float v[4]; };

// ---------------- prep: M1/M2 from w1 ----------------
__global__ void k_prep(const float* __restrict__ w1, float* __restrict__ ws) {
    int g = blockIdx.x * 256 + threadIdx.x;   // 4096
    int cp = g >> 6, c = g & 63;
    float a = w1[cp * 128 + c];
    float b = w1[cp * 128 + 64 + c];
    ws[WS_M1 + g] = a - b;
    ws[WS_M2 + g] = b;
}

// ---------------- squared norms ----------------
__global__ void k_xx(const float* __restrict__ x, float* __restrict__ ws) {
    int g = blockIdx.x * 256 + threadIdx.x;   // 32768
    int b = g >> 12, n = g & 4095;
    const float* xb = x + (size_t)b * Cc * Nn + n;
    float s = 0.f;
    #pragma unroll
    for (int c = 0; c < 64; ++c) { float v = xb[(size_t)c * Nn]; s = fmaf(v, v, s); }
    ws[WS_XX + g] = s;
}

// ---------------- fused pairwise-distance + top-K ----------------
// grid 4096: block = batch b, 8 rows i0..i0+7; 512 threads (8 waves).
// dist rows live in 128 KiB LDS (gfx950: 160 KiB/CU); 1 block/CU.
__global__ __launch_bounds__(512, 2) void k_dist_topk(const float* __restrict__ x,
                                                      const float* __restrict__ ws,
                                                      int* __restrict__ idxo) {
    __shared__ float dist[8 * 4096];          // 128 KiB, linear layout
    __shared__ float xis[64 * 8];             // xi tile [c][r]
    const int t   = threadIdx.x;
    const int blk = blockIdx.x;
    const int b   = blk >> 9;
    const int i0  = (blk & 511) << 3;
    const float* xb  = x + (size_t)b * Cc * Nn;
    const float* xxp = ws + WS_XX + b * Nn;

    if (t < 64) {
        #pragma unroll
        for (int r = 0; r < 8; ++r) xis[t * 8 + r] = xb[(size_t)t * Nn + i0 + r];
    }
    float xxi[8];
    #pragma unroll
    for (int r = 0; r < 8; ++r) xxi[r] = xxp[i0 + r];  // block-uniform
    __syncthreads();

    // ---- distance phase: 2 passes of 2048 j, 4 j per thread, 8 rows ----
    for (int pass = 0; pass < 2; ++pass) {
        float acc[8][4];
        #pragma unroll
        for (int r = 0; r < 8; ++r)
            #pragma unroll
            for (int q = 0; q < 4; ++q) acc[r][q] = 0.f;
        const int jb = (pass << 11) + t * 4;
        #pragma unroll 8
        for (int c = 0; c < 64; ++c) {
            F4 xj = *(const F4*)(xb + (size_t)c * Nn + jb);   // coalesced 16B
            const float* xip = &xis[c * 8];                   // LDS broadcast
            #pragma unroll
            for (int r = 0; r < 8; ++r) {
                float xv = xip[r];
                #pragma unroll
                for (int q = 0; q < 4; ++q)
                    acc[r][q] = fmaf(xv, xj.v[q], acc[r][q]);
            }
        }
        F4 xxj = *(const F4*)(xxp + jb);
        #pragma unroll
        for (int r = 0; r < 8; ++r) {
            F4 pd;
            #pragma unroll
            for (int q = 0; q < 4; ++q)
                pd.v[q] = fmaf(2.f, acc[r][q], -xxi[r]) - xxj.v[q];  // diag exactly 0
            *(F4*)&dist[(r << 12) + jb] = pd;                 // contiguous b128
        }
    }
    __syncthreads();

    // ---- barrier-free top-K: wave w owns row w; lane owns chunk [lane*64,+64) ----
    const int w = t >> 6, lane = t & 63;
    const float* drow = dist + (w << 12);

    // initial scan, lane-rotated order (2-way bank alias = free); keep top-2
    float m1 = NEGINF, m2 = NEGINF; int j1 = 0, j2 = 0;
    for (int m = 0; m < 64; ++m) {
        int mm = (m + lane) & 63;
        int j = (lane << 6) | mm;
        float v = drow[j];
        bool p1 = v > m1;
        bool p2 = v > m2;
        m2 = p1 ? m1 : (p2 ? v : m2);
        j2 = p1 ? j1 : (p2 ? j : j2);
        m1 = p1 ? v : m1;
        j1 = p1 ? j : j1;
    }

    int cnt = 2;
    unsigned rlo = 0, rhi = 0;    // removed mask for OWN chunk
    int outj = 0;
    const int outbase = ((b << 12) + i0 + w) * Kk;

    for (int k = 0; k < Kk; ++k) {
        // global argmax over chunk maxima (lowest index on ties)
        float bv = m1; int bj = j1;
        #pragma unroll
        for (int s = 1; s < 64; s <<= 1) {
            float ov = __shfl_xor(bv, s);
            int   oj = __shfl_xor(bj, s);
            bool take = (ov > bv) || (ov == bv && oj < bj);
            bv = take ? ov : bv; bj = take ? oj : bj;
        }
        if (lane == k) outj = bj;
        const int cw = bj >> 6;
        const int ocnt = __shfl(cnt, cw);      // owner's cache depth (uniform)
        if (lane == cw) {                       // owner: mark removed, pop cache
            int bit = bj & 63;
            if (bit < 32) rlo |= 1u << bit; else rhi |= 1u << (bit - 32);
            m1 = m2; j1 = j2; m2 = NEGINF; cnt = cnt - 1;
        }
        if (ocnt == 1) {                        // owner exhausted -> rare rescan
            unsigned lo = __shfl(rlo, cw), hi = __shfl(rhi, cw);
            int rj = (cw << 6) | lane;
            float rv = drow[rj];                // 2-way bank alias = free
            bool rem = (lane < 32) ? ((lo >> lane) & 1u) : ((hi >> (lane - 32)) & 1u);
            rv = rem ? NEGINF : rv;
            #pragma unroll
            for (int s = 1; s < 64; s <<= 1) {
                float ov = __shfl_xor(rv, s);
                int   oj = __shfl_xor(rj, s);
                bool take = (ov > rv) || (ov == rv && oj < rj);
                rv = take ? ov : rv; rj = take ? oj : rj;
            }
            if (lane == cw) { m1 = rv; j1 = rj; cnt = 1; }
        }
    }
    if (lane < Kk) idxo[outbase + lane] = outj;
}

// ---------------- U = M1.x, Y = M2.x (tiny GEMMs) ----------------
__global__ __launch_bounds__(256) void k_uy(const float* __restrict__ x,
                                            float* __restrict__ ws) {
    __shared__ float xts[64 * 68];
    __shared__ float m1s[64 * 65];
    __shared__ float m2s[64 * 65];
    const int t = threadIdx.x;
    const int b  = blockIdx.x >> 6;
    const int i0 = (blockIdx.x & 63) << 6;
    const float* xb = x + (size_t)b * Cc * Nn;
    const int lane = t & 63, q = t >> 6;

    #pragma unroll
    for (int cc = 0; cc < 16; ++cc) {
        int c = q + cc * 4;
        xts[c * 68 + lane] = xb[(size_t)c * Nn + i0 + lane];
        int gidx = cc * 256 + t;
        int cp = gidx >> 6, c2 = gidx & 63;
        m1s[cp * 65 + c2] = ws[WS_M1 + gidx];
        m2s[cp * 65 + c2] = ws[WS_M2 + gidx];
    }
    __syncthreads();

    float accU[16], accY[16];
    #pragma unroll
    for (int m = 0; m < 16; ++m) { accU[m] = 0.f; accY[m] = 0.f; }

    #pragma unroll 4
    for (int c = 0; c < 64; ++c) {
        float a1 = m1s[lane * 65 + c];
        float a2 = m2s[lane * 65 + c];
        const F4* xr = (const F4*)&xts[c * 68 + q * 16];
        #pragma unroll
        for (int mm = 0; mm < 4; ++mm) {
            F4 xv = xr[mm];
            #pragma unroll
            for (int ii = 0; ii < 4; ++ii) {
                accU[mm * 4 + ii] = fmaf(a1, xv.v[ii], accU[mm * 4 + ii]);
                accY[mm * 4 + ii] = fmaf(a2, xv.v[ii], accY[mm * 4 + ii]);
            }
        }
    }
    float* Up = ws + WS_U + ((size_t)(b << 12) + i0 + q * 16) * 64 + lane;
    float* Yp = ws + WS_Y + ((size_t)(b << 12) + i0 + q * 16) * 64 + lane;
    #pragma unroll
    for (int m = 0; m < 16; ++m) { Up[(size_t)m * 64] = accU[m]; Yp[(size_t)m * 64] = accY[m]; }
}

// ---------------- BN statistics (deterministic two-stage) ----------------
__global__ __launch_bounds__(256) void k_stats(const float* __restrict__ wsf,
                                               const int* __restrict__ idxI,
                                               float* __restrict__ psum,
                                               float* __restrict__ psq) {
    const int t = threadIdx.x;
    const int c = t & 63, w = t >> 6;
    const int b  = blockIdx.x >> 7;           // grid 1024
    const int n0 = (blockIdx.x & 127) << 5;   // 32 n per block
    const float* U = wsf + WS_U;
    const float* Y = wsf + WS_Y;
    float s = 0.f, s2 = 0.f;
    for (int nl = 0; nl < 8; ++nl) {
        const int n = (b << 12) + n0 + (nl << 2) + w;
        const int* ip = idxI + n * Kk;
        int jj[Kk];
        #pragma unroll
        for (int k = 0; k < Kk; ++k) jj[k] = ip[k];     // uniform scalar prefetch
        const float uv = U[(size_t)n * 64 + c];
        #pragma unroll
        for (int k = 0; k < Kk; ++k) {                  // 20 independent loads
            float yv = Y[(size_t)((b << 12) | jj[k]) * 64 + c];
            float h = uv + yv;
            s += h; s2 = fmaf(h, h, s2);
        }
    }
    __shared__ float rs[4][64], rq[4][64];
    rs[w][c] = s; rq[w][c] = s2;
    __syncthreads();
    if (t < 64) {
        float a  = rs[0][t] + rs[1][t] + rs[2][t] + rs[3][t];
        float b2 = rq[0][t] + rq[1][t] + rq[2][t] + rq[3][t];
        psum[blockIdx.x * 64 + t] = a;
        psq [blockIdx.x * 64 + t] = b2;
    }
}

__global__ __launch_bounds__(256) void k_fin(const float* __restrict__ psum,
                                             const float* __restrict__ psq,
                                             const float* __restrict__ gamma,
                                             const float* __restrict__ beta,
                                             float* __restrict__ sc, float* __restrict__ sh) {
    const int t = threadIdx.x;
    const int c = t & 63, q = t >> 6;
    float s = 0.f, s2 = 0.f;
    for (int i = q; i < 1024; i += 4) { s += psum[i * 64 + c]; s2 += psq[i * 64 + c]; }
    __shared__ float rs[4][64], rq[4][64];
    rs[q][c] = s; rq[q][c] = s2;
    __syncthreads();
    if (t < 64) {
        float a  = rs[0][t] + rs[1][t] + rs[2][t] + rs[3][t];
        float b2 = rq[0][t] + rq[1][t] + rq[2][t] + rq[3][t];
        const float inv = 1.f / 655360.f;
        float mean = a * inv;
        float var  = b2 * inv - mean * mean;
        float scale = gamma[t] * rsqrtf(var + 1e-5f);
        sc[t] = scale;
        sh[t] = beta[t] - mean * scale;
    }
}

// ---------------- BN+relu+GEMM(w2)+max_k+transpose ----------------
__global__ __launch_bounds__(256) void k_out(const float* __restrict__ wsf,
                                             const int* __restrict__ idxI,
                                             const float* __restrict__ w2,
                                             float* __restrict__ out) {
    __shared__ float gbuf[4 * Kk * 64];       // per-wave private regions
    __shared__ float outT[64 * 65];
    const int t = threadIdx.x;
    const int lane = t & 63, w = t >> 6;
    const int b = blockIdx.x >> 6;
    const int n0 = (blockIdx.x & 63) << 6;
    const float* U = wsf + WS_U;
    const float* Y = wsf + WS_Y;

    float w2r[64];
    #pragma unroll
    for (int cc = 0; cc < 16; ++cc) {
        F4 v = *(const F4*)&w2[lane * 64 + cc * 4];
        #pragma unroll
        for (int ii = 0; ii < 4; ++ii) w2r[cc * 4 + ii] = v.v[ii];
    }
    const float sc = wsf[WS_SC + lane];
    const float sh = wsf[WS_SH + lane];

    for (int sg = 0; sg < 16; ++sg) {
        const int n = (b << 12) + n0 + sg * 4 + w;
        const float uv = U[(size_t)n * 64 + lane];
        const int* ip = idxI + n * Kk;
        int jj[Kk];
        #pragma unroll
        for (int k = 0; k < Kk; ++k) jj[k] = ip[k];     // uniform prefetch
        #pragma unroll
        for (int k = 0; k < Kk; ++k) {                  // independent Y loads
            float hv = uv + Y[(size_t)((b << 12) | jj[k]) * 64 + lane];
            float g = fmaf(hv, sc, sh);
            gbuf[(w * Kk + k) * 64 + lane] = fmaxf(g, 0.f);
        }
        __syncthreads();
        float vmax = NEGINF;
        #pragma unroll 4
        for (int k = 0; k < Kk; ++k) {
            const F4* gp = (const F4*)&gbuf[(w * Kk + k) * 64];
            float a = 0.f;
            #pragma unroll
            for (int cc = 0; cc < 16; ++cc) {
                F4 gv = gp[cc];
                a = fmaf(gv.v[0], w2r[cc * 4 + 0], a);
                a = fmaf(gv.v[1], w2r[cc * 4 + 1], a);
                a = fmaf(gv.v[2], w2r[cc * 4 + 2], a);
                a = fmaf(gv.v[3], w2r[cc * 4 + 3], a);
            }
            vmax = fmaxf(vmax, a);
        }
        outT[lane * 65 + sg * 4 + w] = vmax;
        __syncthreads();
    }
    #pragma unroll
    for (int m = 0; m < 16; ++m) {
        int row = w + m * 4;
        out[((size_t)(b * 64 + row)) * 4096 + n0 + lane] = outT[row * 65 + lane];
    }
}

// ---------------- launch ----------------
extern "C" void kernel_launch(void* const* d_in, const int* in_sizes, int n_in,
                              void* d_out, int out_size, void* d_ws, size_t ws_size,
                              hipStream_t stream) {
    (void)in_sizes; (void)n_in; (void)out_size; (void)ws_size;
    const float* x     = (const float*)d_in[0];
    const float* w1    = (const float*)d_in[1];
    const float* gamma = (const float*)d_in[2];
    const float* beta  = (const float*)d_in[3];
    const float* w2    = (const float*)d_in[4];
    float* out = (float*)d_out;
    float* wsf = (float*)d_ws;
    int*  idxI = (int*)(wsf + WS_IDX);

    hipLaunchKernelGGL(k_prep,      dim3(16),   dim3(256), 0, stream, w1, wsf);
    hipLaunchKernelGGL(k_xx,        dim3(128),  dim3(256), 0, stream, x, wsf);
    hipLaunchKernelGGL(k_dist_topk, dim3(4096), dim3(512), 0, stream, x, wsf, idxI);
    hipLaunchKernelGGL(k_uy,        dim3(512),  dim3(256), 0, stream, x, wsf);
    hipLaunchKernelGGL(k_stats,     dim3(1024), dim3(256), 0, stream, wsf, idxI,
                       wsf + WS_PS, wsf + WS_PQ);
    hipLaunchKernelGGL(k_fin,       dim3(1),    dim3(256), 0, stream,
                       wsf + WS_PS, wsf + WS_PQ, gamma, beta, wsf + WS_SC, wsf + WS_SH);
    hipLaunchKernelGGL(k_out,       dim3(512),  dim3(256), 0, stream, wsf, idxI, w2, out);
}